// Round 4
// baseline (9954.897 us; speedup 1.0000x reference)
//
#include <hip/hip_runtime.h>
#include <math.h>

#define BATCH    8192
#define TSTEPS   128
#define SDIM     16
#define HID      50
#define NGATE    200
#define IN0      17
#define FC1N     25
#define BT       4      // samples per block
#define NTHREADS 448    // 7 waves; 400 gate workers
#define XP       20     // padded x row: 4 quarters of 5 (17 used, [16]=prev_delta)
#define HP       56     // padded h/c row: 4 quarters of 14 (50 used)
#define WFP      56     // wfc1 row pad

__device__ __forceinline__ float sig_u(float x) {
    float e = __expf(-x);
    return __builtin_amdgcn_rcpf(1.0f + e);
}
__device__ __forceinline__ float tanh_u(float x) {
    float e = __expf(-2.0f * x);
    return fmaf(2.0f, __builtin_amdgcn_rcpf(1.0f + e), -1.0f);
}

__global__ __launch_bounds__(NTHREADS, 4)
void lstm2_pairsplit_kernel(const float* __restrict__ feat,
                            const float* __restrict__ w_ih0,
                            const float* __restrict__ w_hh0,
                            const float* __restrict__ b_0,
                            const float* __restrict__ w_ih1,
                            const float* __restrict__ w_hh1,
                            const float* __restrict__ b_1,
                            const float* __restrict__ w_fc1,
                            const float* __restrict__ b_fc1,
                            const float* __restrict__ w_fc2,
                            const float* __restrict__ b_fc2,
                            float* __restrict__ out)
{
    __shared__ __align__(16) float sm_x[BT][XP];
    __shared__ __align__(16) float sm_h0[BT][HP];
    __shared__ __align__(16) float sm_c0[BT][HP];
    __shared__ __align__(16) float sm_h1[BT][HP];
    __shared__ __align__(16) float sm_c1[BT][HP];
    __shared__ __align__(16) float sm_act[BT][NGATE];
    __shared__ __align__(16) float sm_r[BT][FC1N + 3];
    __shared__ __align__(16) float sm_wfc1[FC1N][WFP];
    __shared__ float sm_wfc2[FC1N], sm_bfc1[FC1N], sm_bfc2v;

    const int tid = threadIdx.x;
    const int b0  = blockIdx.x * BT;

    // ---- gate worker mapping: thread (p,q) owns rows {2p,2p+1}, k-quarter q
    const bool worker = (tid < 2 * NGATE);           // 400 workers
    const int  q  = tid & 3;
    const int  p  = worker ? (tid >> 2) : 0;         // clamp for safe preamble loads
    const int  r0 = 2 * p, r1 = r0 + 1;
    const bool tanh_pair = (p >= 50 && p < 75);      // rows 100..149 = g-gate

    // ---- per-thread weight registers: 94 floats + 4 biases
    float wx0[5], wx1[5];
    float wh0a[14], wh0b[14], wi1a[14], wi1b[14], wh1a[14], wh1b[14];
    #pragma unroll
    for (int j = 0; j < 5; ++j) {
        int k = q * 5 + j;
        wx0[j] = (k < IN0) ? w_ih0[r0 * IN0 + k] : 0.0f;
        wx1[j] = (k < IN0) ? w_ih0[r1 * IN0 + k] : 0.0f;
    }
    #pragma unroll
    for (int j = 0; j < 14; ++j) {
        int k = q * 14 + j;
        bool v = (k < HID);
        wh0a[j] = v ? w_hh0[r0 * HID + k] : 0.0f;
        wh0b[j] = v ? w_hh0[r1 * HID + k] : 0.0f;
        wi1a[j] = v ? w_ih1[r0 * HID + k] : 0.0f;
        wi1b[j] = v ? w_ih1[r1 * HID + k] : 0.0f;
        wh1a[j] = v ? w_hh1[r0 * HID + k] : 0.0f;
        wh1b[j] = v ? w_hh1[r1 * HID + k] : 0.0f;
    }
    const float bA0 = b_0[r0], bB0 = b_0[r1];
    const float bA1 = b_1[r0], bB1 = b_1[r1];

    // ---- hoisted phase mappings
    const int  cb = tid / HID, cj = tid - cb * HID;          // cell tasks (tid<200)
    const bool do_cell = (tid < BT * HID);
    const int  fb = tid / FC1N, fj = tid - fb * FC1N;        // fc1 tasks (tid<100)
    const bool do_fc1 = (tid < BT * FC1N);
    const bool do_feat = (tid < BT * SDIM);                  // 64 feature loaders
    const int  xb = tid >> 4, xk = tid & 15;
    const size_t fbase = (size_t)(b0 + (do_feat ? xb : 0)) * (TSTEPS * SDIM) + xk;

    // ---- preamble: zero state, stage FC weights
    for (int i = tid; i < BT * HP; i += NTHREADS) {
        (&sm_h0[0][0])[i] = 0.0f; (&sm_c0[0][0])[i] = 0.0f;
        (&sm_h1[0][0])[i] = 0.0f; (&sm_c1[0][0])[i] = 0.0f;
    }
    for (int i = tid; i < BT * XP; i += NTHREADS) (&sm_x[0][0])[i] = 0.0f;
    for (int i = tid; i < FC1N * WFP; i += NTHREADS) {
        int j = i / WFP, k = i - j * WFP;
        sm_wfc1[j][k] = (k < HID) ? w_fc1[j * HID + k] : 0.0f;
    }
    if (tid < FC1N) { sm_wfc2[tid] = w_fc2[tid]; sm_bfc1[tid] = b_fc1[tid]; }
    if (tid == 0)   { sm_bfc2v = b_fc2[0]; }

    // RACE FIX (round-3 bug): sm_x zero-init above spans waves 0 AND 1
    // (flat 0..79), while t=0 staging below is wave 0 writing flat 0..75.
    // Without this barrier, wave 1's zero store can land AFTER wave 0's
    // feature store and clobber batch 3's t=0 features (flat 64..75).
    __syncthreads();

    if (do_feat) sm_x[xb][xk] = feat[fbase];
    __syncthreads();

    const int q5 = q * 5, q14 = q * 14;

    for (int t = 0; t < TSTEPS; ++t) {
        // prefetch next step's features (latency hidden across the whole step)
        float fnext = 0.0f;
        if (do_feat && (t + 1 < TSTEPS)) fnext = feat[fbase + (size_t)(t + 1) * SDIM];

        // ============ layer-0 gates ============
        {
            float acc0[BT], acc1[BT];
            #pragma unroll
            for (int b = 0; b < BT; ++b) {
                acc0[b] = (q == 0) ? bA0 : 0.0f;
                acc1[b] = (q == 0) ? bB0 : 0.0f;
            }
            #pragma unroll
            for (int b = 0; b < BT; ++b) {
                const float* xq = &sm_x[b][q5];
                #pragma unroll
                for (int j = 0; j < 5; ++j) {
                    float xv = xq[j];
                    acc0[b] += wx0[j] * xv;
                    acc1[b] += wx1[j] * xv;
                }
                const float2* hq = (const float2*)&sm_h0[b][q14];
                #pragma unroll
                for (int j = 0; j < 7; ++j) {
                    float2 hv = hq[j];
                    acc0[b] += wh0a[2*j] * hv.x + wh0a[2*j+1] * hv.y;
                    acc1[b] += wh0b[2*j] * hv.x + wh0b[2*j+1] * hv.y;
                }
            }
            float s0 = 0.0f, s1 = 0.0f;
            #pragma unroll
            for (int b = 0; b < BT; ++b) {
                float t0 = acc0[b] + __shfl_xor(acc0[b], 1); t0 += __shfl_xor(t0, 2);
                float t1 = acc1[b] + __shfl_xor(acc1[b], 1); t1 += __shfl_xor(t1, 2);
                if (q == b) { s0 = t0; s1 = t1; }
            }
            float v0 = tanh_pair ? tanh_u(s0) : sig_u(s0);
            float v1 = tanh_pair ? tanh_u(s1) : sig_u(s1);
            if (worker) { float2 wv; wv.x = v0; wv.y = v1; *(float2*)&sm_act[q][r0] = wv; }
        }
        __syncthreads();

        // ============ layer-0 cell update ============
        if (do_cell) {
            float i_ = sm_act[cb][cj];
            float f_ = sm_act[cb][HID + cj];
            float g_ = sm_act[cb][2 * HID + cj];
            float o_ = sm_act[cb][3 * HID + cj];
            float c  = f_ * sm_c0[cb][cj] + i_ * g_;
            sm_c0[cb][cj] = c;
            sm_h0[cb][cj] = o_ * tanh_u(c);
        }
        __syncthreads();

        // ============ layer-1 gates ============
        {
            float acc0[BT], acc1[BT];
            #pragma unroll
            for (int b = 0; b < BT; ++b) {
                acc0[b] = (q == 0) ? bA1 : 0.0f;
                acc1[b] = (q == 0) ? bB1 : 0.0f;
            }
            #pragma unroll
            for (int b = 0; b < BT; ++b) {
                const float2* hq = (const float2*)&sm_h0[b][q14];
                #pragma unroll
                for (int j = 0; j < 7; ++j) {
                    float2 hv = hq[j];
                    acc0[b] += wi1a[2*j] * hv.x + wi1a[2*j+1] * hv.y;
                    acc1[b] += wi1b[2*j] * hv.x + wi1b[2*j+1] * hv.y;
                }
                const float2* gq = (const float2*)&sm_h1[b][q14];
                #pragma unroll
                for (int j = 0; j < 7; ++j) {
                    float2 hv = gq[j];
                    acc0[b] += wh1a[2*j] * hv.x + wh1a[2*j+1] * hv.y;
                    acc1[b] += wh1b[2*j] * hv.x + wh1b[2*j+1] * hv.y;
                }
            }
            float s0 = 0.0f, s1 = 0.0f;
            #pragma unroll
            for (int b = 0; b < BT; ++b) {
                float t0 = acc0[b] + __shfl_xor(acc0[b], 1); t0 += __shfl_xor(t0, 2);
                float t1 = acc1[b] + __shfl_xor(acc1[b], 1); t1 += __shfl_xor(t1, 2);
                if (q == b) { s0 = t0; s1 = t1; }
            }
            float v0 = tanh_pair ? tanh_u(s0) : sig_u(s0);
            float v1 = tanh_pair ? tanh_u(s1) : sig_u(s1);
            if (worker) { float2 wv; wv.x = v0; wv.y = v1; *(float2*)&sm_act[q][r0] = wv; }
        }
        __syncthreads();

        // ============ layer-1 cell update ============
        if (do_cell) {
            float i_ = sm_act[cb][cj];
            float f_ = sm_act[cb][HID + cj];
            float g_ = sm_act[cb][2 * HID + cj];
            float o_ = sm_act[cb][3 * HID + cj];
            float c  = f_ * sm_c1[cb][cj] + i_ * g_;
            sm_c1[cb][cj] = c;
            sm_h1[cb][cj] = o_ * tanh_u(c);
        }
        __syncthreads();

        // ============ fc1 + relu ============
        if (do_fc1) {
            const float2* hv = (const float2*)sm_h1[fb];
            const float2* wv = (const float2*)sm_wfc1[fj];
            float p0 = sm_bfc1[fj], p1 = 0.0f;
            #pragma unroll
            for (int j2 = 0; j2 < 25; ++j2) {
                float2 h = hv[j2], w = wv[j2];
                p0 += w.x * h.x; p1 += w.y * h.y;
            }
            sm_r[fb][fj] = fmaxf(p0 + p1, 0.0f);
        }
        __syncthreads();

        // ============ fc2 -> delta, write out, feed back; stage next features ============
        if (tid < BT) {
            float d = sm_bfc2v;
            #pragma unroll
            for (int j2 = 0; j2 < FC1N; ++j2) d += sm_wfc2[j2] * sm_r[tid][j2];
            out[(size_t)(b0 + tid) * TSTEPS + t] = d;
            sm_x[tid][16] = d;
        }
        if (do_feat && (t + 1 < TSTEPS)) sm_x[xb][xk] = fnext;  // disjoint from [16]
        __syncthreads();
    }
}

extern "C" void kernel_launch(void* const* d_in, const int* in_sizes, int n_in,
                              void* d_out, int out_size, void* d_ws, size_t ws_size,
                              hipStream_t stream) {
    const float* feat  = (const float*)d_in[0];
    const float* w_ih0 = (const float*)d_in[1];
    const float* w_hh0 = (const float*)d_in[2];
    const float* b_0   = (const float*)d_in[3];
    const float* w_ih1 = (const float*)d_in[4];
    const float* w_hh1 = (const float*)d_in[5];
    const float* b_1   = (const float*)d_in[6];
    const float* w_fc1 = (const float*)d_in[7];
    const float* b_fc1 = (const float*)d_in[8];
    const float* w_fc2 = (const float*)d_in[9];
    const float* b_fc2 = (const float*)d_in[10];
    float* out = (float*)d_out;

    dim3 grid(BATCH / BT);
    dim3 block(NTHREADS);
    hipLaunchKernelGGL(lstm2_pairsplit_kernel, grid, block, 0, stream,
                       feat, w_ih0, w_hh0, b_0, w_ih1, w_hh1, b_1,
                       w_fc1, b_fc1, w_fc2, b_fc2, out);
}

// Round 5
// 1170.570 us; speedup vs baseline: 8.5043x; 8.5043x over previous
//
#include <hip/hip_runtime.h>
#include <hip/hip_bf16.h>
#include <math.h>

#define BATCH    8192
#define TSTEPS   128
#define SDIM     16
#define HID      50
#define IN0      17     // SDIM + 1 (prev_delta)
#define BT       16     // samples per block = MFMA N
#define NTHREADS 256    // 4 waves

// K-slot layouts (bf16 elements):
//  X0 (L0 input):  [x(0..15) | delta(16) | h0(17..66) | zero(67..71)]   K0P=72
//  X1 (L1 input):  [h1(0..49) | zero(50,51) | h0(52..101) | zero(102,103)] K1P=104
//  FC:             [h1(0..49) | (cols 50..63 zero-weighted)]            KFP=64
#define K0P 72
#define K1P 104
#define KFP 64

// LDS element offsets (bf16 elements, 2B each). Total 80128 el = 160256 B.
#define OFF_W0H 0
#define OFF_W0L 14400
#define OFF_W1H 28800
#define OFF_W1L 49600
#define OFF_WFH 70400
#define OFF_WFL 72448
#define OFF_X0H 74496
#define OFF_X0L 75648
#define OFF_X1H 76800
#define OFF_X1L 78464
#define LDS_BYTES (80128 * 2)

typedef __attribute__((ext_vector_type(8))) short   short8;
typedef __attribute__((ext_vector_type(4))) float   floatx4;

__device__ __forceinline__ float sig_u(float x) {
    float e = __expf(-x);
    return __builtin_amdgcn_rcpf(1.0f + e);
}
__device__ __forceinline__ float tanh_u(float x) {
    float e = __expf(-2.0f * x);
    return fmaf(2.0f, __builtin_amdgcn_rcpf(1.0f + e), -1.0f);
}
// fp32 v -> bf16 hi + bf16 lo (v ~= hi + lo to ~2^-17 relative)
__device__ __forceinline__ void bsplit(float v, __hip_bfloat16* hp, __hip_bfloat16* lp) {
    __hip_bfloat16 h = __float2bfloat16(v);
    *hp = h;
    *lp = __float2bfloat16(v - __bfloat162float(h));
}

#define MFMA(a, b, c) __builtin_amdgcn_mfma_f32_16x16x32_bf16((a), (b), (c), 0, 0, 0)

__global__ __launch_bounds__(NTHREADS, 1)
void lstm2_mfma_kernel(const float* __restrict__ feat,
                       const float* __restrict__ w_ih0,
                       const float* __restrict__ w_hh0,
                       const float* __restrict__ b_0,
                       const float* __restrict__ w_ih1,
                       const float* __restrict__ w_hh1,
                       const float* __restrict__ b_1,
                       const float* __restrict__ w_fc1,
                       const float* __restrict__ b_fc1,
                       const float* __restrict__ w_fc2,
                       const float* __restrict__ b_fc2,
                       float* __restrict__ out)
{
    extern __shared__ __hip_bfloat16 sm[];
    __hip_bfloat16* W0h = sm + OFF_W0H;
    __hip_bfloat16* W0l = sm + OFF_W0L;
    __hip_bfloat16* W1h = sm + OFF_W1H;
    __hip_bfloat16* W1l = sm + OFF_W1L;
    __hip_bfloat16* Wfh = sm + OFF_WFH;
    __hip_bfloat16* Wfl = sm + OFF_WFL;
    __hip_bfloat16* X0h = sm + OFF_X0H;
    __hip_bfloat16* X0l = sm + OFF_X0L;
    __hip_bfloat16* X1h = sm + OFF_X1H;
    __hip_bfloat16* X1l = sm + OFF_X1L;

    const int tid  = threadIdx.x;
    const int lane = tid & 63;
    const int wv   = tid >> 6;        // wave id 0..3
    const int quad = lane >> 4;       // 0..3
    const int col  = lane & 15;       // sample within block
    const int b0   = blockIdx.x * BT;

    // ---- stage weights into LDS, unit-interleaved rows: row 4j+q = gate q of unit j
    //      (PyTorch order q: 0=i,1=f,2=g,3=o; orig row = q*50 + j)
    for (int i = tid; i < 200 * K0P; i += NTHREADS) {
        int row = i / K0P, k = i - row * K0P;
        int j = row >> 2, q = row & 3, orig = q * HID + j;
        float v = 0.0f;
        if (k < IN0)            v = w_ih0[orig * IN0 + k];
        else if (k < IN0 + HID) v = w_hh0[orig * HID + (k - IN0)];
        bsplit(v, &W0h[i], &W0l[i]);
    }
    for (int i = tid; i < 200 * K1P; i += NTHREADS) {
        int row = i / K1P, k = i - row * K1P;
        int j = row >> 2, q = row & 3, orig = q * HID + j;
        float v = 0.0f;
        if (k < HID)                  v = w_hh1[orig * HID + k];        // x h1 (recurrent)
        else if (k >= 52 && k < 52 + HID) v = w_ih1[orig * HID + (k - 52)];  // x h0
        bsplit(v, &W1h[i], &W1l[i]);
    }
    for (int i = tid; i < 32 * KFP; i += NTHREADS) {
        int row = i >> 6, k = i & 63;
        float v = (row < 25 && k < HID) ? w_fc1[row * HID + k] : 0.0f;
        bsplit(v, &Wfh[i], &Wfl[i]);
    }
    // ---- zero state planes
    for (int i = tid; i < BT * K0P; i += NTHREADS) { ((short*)X0h)[i] = 0; ((short*)X0l)[i] = 0; }
    for (int i = tid; i < BT * K1P; i += NTHREADS) { ((short*)X1h)[i] = 0; ((short*)X1l)[i] = 0; }
    __syncthreads();   // zeroing complete before t=0 feature staging (round-3 lesson)

    // ---- t=0 features
    const int xs = tid >> 4, xk = tid & 15;
    const size_t fbase = (size_t)(b0 + xs) * (TSTEPS * SDIM) + xk;
    { float v = feat[fbase]; bsplit(v, &X0h[xs * K0P + xk], &X0l[xs * K0P + xk]); }

    // ---- wave -> M-tile assignment: {0-2},{3-5},{6-9},{10-12}
    const int tstart = wv * 3 + (wv == 3 ? 1 : 0);
    const int tcnt   = 3 + (wv == 2 ? 1 : 0);

    // ---- per-lane biases for the wave's units (acc layout: reg rho = gate rho of unit u)
    floatx4 bias0[4], bias1[4];
    #pragma unroll
    for (int ti = 0; ti < 4; ++ti) {
        int mt = tstart + ti, u = 4 * mt + quad;
        floatx4 z = {0.f, 0.f, 0.f, 0.f};
        bias0[ti] = z; bias1[ti] = z;
        if (ti < tcnt && u < HID) {
            bias0[ti][0] = b_0[u]; bias0[ti][1] = b_0[HID + u];
            bias0[ti][2] = b_0[2 * HID + u]; bias0[ti][3] = b_0[3 * HID + u];
            bias1[ti][0] = b_1[u]; bias1[ti][1] = b_1[HID + u];
            bias1[ti][2] = b_1[2 * HID + u]; bias1[ti][3] = b_1[3 * HID + u];
        }
    }
    // ---- FC constants (wave 0 only): fc rows are NOT interleaved; row = 16*tf + quad*4 + rho
    floatx4 w2r[2], bfr[2];
    { floatx4 z = {0.f,0.f,0.f,0.f}; w2r[0]=z; w2r[1]=z; bfr[0]=z; bfr[1]=z; }
    float bf2 = 0.0f;
    if (wv == 0) {
        bf2 = b_fc2[0];
        #pragma unroll
        for (int tf = 0; tf < 2; ++tf)
            #pragma unroll
            for (int r5 = 0; r5 < 4; ++r5) {
                int r = 16 * tf + quad * 4 + r5;
                if (r < 25) { w2r[tf][r5] = w_fc2[r]; bfr[tf][r5] = b_fc1[r]; }
            }
    }

    float c0s[4] = {0.f, 0.f, 0.f, 0.f};
    float c1s[4] = {0.f, 0.f, 0.f, 0.f};
    const short8 zf = (short8)0;
    __syncthreads();

    for (int t = 0; t < TSTEPS; ++t) {
        // prefetch next-step features (consumed in P5; latency hidden across phases)
        float fnext = (t + 1 < TSTEPS) ? feat[fbase + (size_t)(t + 1) * SDIM] : 0.0f;

        // ===== P1: layer-0 gates via 3-product split-bf16 MFMA =====
        floatx4 acc[4];
        #pragma unroll
        for (int ti = 0; ti < 4; ++ti) acc[ti] = bias0[ti];
        #pragma unroll
        for (int kt = 0; kt < 3; ++kt) {
            int k0 = 32 * kt + quad * 8;
            short8 bh = zf, bl = zf;
            if (k0 < K0P) {
                bh = *(const short8*)(X0h + col * K0P + k0);
                bl = *(const short8*)(X0l + col * K0P + k0);
            }
            #pragma unroll
            for (int ti = 0; ti < 4; ++ti) {
                if (ti >= tcnt) continue;
                int row = 16 * (tstart + ti) + col;
                short8 ah = zf, al = zf;
                if (row < 200 && k0 < K0P) {
                    ah = *(const short8*)(W0h + row * K0P + k0);
                    al = *(const short8*)(W0l + row * K0P + k0);
                }
                acc[ti] = MFMA(ah, bh, acc[ti]);
                acc[ti] = MFMA(ah, bl, acc[ti]);
                acc[ti] = MFMA(al, bh, acc[ti]);
            }
        }
        __syncthreads();   // B1: all X0 frag reads done before h0 writes

        // ===== P2: layer-0 cell update fully in registers =====
        #pragma unroll
        for (int ti = 0; ti < 4; ++ti) {
            if (ti >= tcnt) continue;
            int u = 4 * (tstart + ti) + quad;
            float i_ = sig_u(acc[ti][0]);
            float f_ = sig_u(acc[ti][1]);
            float g_ = tanh_u(acc[ti][2]);
            float o_ = sig_u(acc[ti][3]);
            float c  = f_ * c0s[ti] + i_ * g_;
            c0s[ti]  = c;
            float h  = o_ * tanh_u(c);
            __hip_bfloat16 hh, hl; bsplit(h, &hh, &hl);
            X1h[col * K1P + 52 + u] = hh;  X1l[col * K1P + 52 + u] = hl;   // L1 input
            X0h[col * K0P + IN0 + u] = hh; X0l[col * K0P + IN0 + u] = hl;  // next-step L0 input
        }
        __syncthreads();   // B2: h0 staged before L1 reads

        // ===== P3: layer-1 gates =====
        floatx4 acc1[4];
        #pragma unroll
        for (int ti = 0; ti < 4; ++ti) acc1[ti] = bias1[ti];
        #pragma unroll
        for (int kt = 0; kt < 4; ++kt) {
            int k0 = 32 * kt + quad * 8;
            short8 bh = zf, bl = zf;
            if (k0 < K1P) {
                bh = *(const short8*)(X1h + col * K1P + k0);
                bl = *(const short8*)(X1l + col * K1P + k0);
            }
            #pragma unroll
            for (int ti = 0; ti < 4; ++ti) {
                if (ti >= tcnt) continue;
                int row = 16 * (tstart + ti) + col;
                short8 ah = zf, al = zf;
                if (row < 200 && k0 < K1P) {
                    ah = *(const short8*)(W1h + row * K1P + k0);
                    al = *(const short8*)(W1l + row * K1P + k0);
                }
                acc1[ti] = MFMA(ah, bh, acc1[ti]);
                acc1[ti] = MFMA(ah, bl, acc1[ti]);
                acc1[ti] = MFMA(al, bh, acc1[ti]);
            }
        }
        __syncthreads();   // B3: X1 frag reads done before h1 writes

        // ===== P4: layer-1 cell update =====
        #pragma unroll
        for (int ti = 0; ti < 4; ++ti) {
            if (ti >= tcnt) continue;
            int u = 4 * (tstart + ti) + quad;
            float i_ = sig_u(acc1[ti][0]);
            float f_ = sig_u(acc1[ti][1]);
            float g_ = tanh_u(acc1[ti][2]);
            float o_ = sig_u(acc1[ti][3]);
            float c  = f_ * c1s[ti] + i_ * g_;
            c1s[ti]  = c;
            float h  = o_ * tanh_u(c);
            __hip_bfloat16 hh, hl; bsplit(h, &hh, &hl);
            X1h[col * K1P + u] = hh;  X1l[col * K1P + u] = hl;   // h1: FC input + next-step L1
        }
        __syncthreads();   // B4: h1 staged before FC reads

        // ===== P5: FC head (wave 0, MFMA) + feature staging (all waves) =====
        if (wv == 0) {
            floatx4 accf[2]; accf[0] = bfr[0]; accf[1] = bfr[1];
            #pragma unroll
            for (int kt = 0; kt < 2; ++kt) {
                int k0 = 32 * kt + quad * 8;   // <= 56 < 64: always stored
                short8 bh = *(const short8*)(X1h + col * K1P + k0);   // cols 50..63 hit pad/h0 — zero-weighted
                short8 bl = *(const short8*)(X1l + col * K1P + k0);
                #pragma unroll
                for (int tf = 0; tf < 2; ++tf) {
                    int row = 16 * tf + col;
                    short8 ah = *(const short8*)(Wfh + row * KFP + k0);
                    short8 al = *(const short8*)(Wfl + row * KFP + k0);
                    accf[tf] = MFMA(ah, bh, accf[tf]);
                    accf[tf] = MFMA(ah, bl, accf[tf]);
                    accf[tf] = MFMA(al, bh, accf[tf]);
                }
            }
            float p = 0.0f;
            #pragma unroll
            for (int tf = 0; tf < 2; ++tf)
                #pragma unroll
                for (int r5 = 0; r5 < 4; ++r5)
                    p += w2r[tf][r5] * fmaxf(accf[tf][r5], 0.0f);
            p += __shfl_xor(p, 16);
            p += __shfl_xor(p, 32);
            float d = p + bf2;
            if (lane < 16) {
                out[(size_t)(b0 + lane) * TSTEPS + t] = d;
                __hip_bfloat16 dh, dl; bsplit(d, &dh, &dl);
                X0h[lane * K0P + 16] = dh; X0l[lane * K0P + 16] = dl;   // prev_delta feedback
            }
        }
        if (t + 1 < TSTEPS) {
            __hip_bfloat16 fh, fl; bsplit(fnext, &fh, &fl);
            X0h[xs * K0P + xk] = fh; X0l[xs * K0P + xk] = fl;
        }
        __syncthreads();   // B5: X0 fully staged for next step
    }
}

extern "C" void kernel_launch(void* const* d_in, const int* in_sizes, int n_in,
                              void* d_out, int out_size, void* d_ws, size_t ws_size,
                              hipStream_t stream) {
    const float* feat  = (const float*)d_in[0];
    const float* w_ih0 = (const float*)d_in[1];
    const float* w_hh0 = (const float*)d_in[2];
    const float* b_0   = (const float*)d_in[3];
    const float* w_ih1 = (const float*)d_in[4];
    const float* w_hh1 = (const float*)d_in[5];
    const float* b_1   = (const float*)d_in[6];
    const float* w_fc1 = (const float*)d_in[7];
    const float* b_fc1 = (const float*)d_in[8];
    const float* w_fc2 = (const float*)d_in[9];
    const float* b_fc2 = (const float*)d_in[10];
    float* out = (float*)d_out;

    // 160 KB dynamic LDS (> 64 KB default cap) — idempotent, safe per call
    hipFuncSetAttribute((const void*)lstm2_mfma_kernel,
                        hipFuncAttributeMaxDynamicSharedMemorySize, LDS_BYTES);

    dim3 grid(BATCH / BT);   // 512 blocks; 1 block/CU (LDS-bound) -> 2 CU rounds
    dim3 block(NTHREADS);
    hipLaunchKernelGGL(lstm2_mfma_kernel, grid, block, LDS_BYTES, stream,
                       feat, w_ih0, w_hh0, b_0, w_ih1, w_hh1, b_1,
                       w_fc1, b_fc1, w_fc2, b_fc2, out);
}

// Round 6
// 480.078 us; speedup vs baseline: 20.7360x; 2.4383x over previous
//
#include <hip/hip_runtime.h>
#include <math.h>

#define BATCH    8192
#define TSTEPS   128
#define SDIM     16
#define HID      50
#define IN0      17     // SDIM + 1 (prev_delta)
#define BT       16     // samples per block = MFMA N
#define NTHREADS 256    // 4 waves; 2 blocks/CU target

// K-slot layouts (fp16 elements):
//  X0 (L0 input):  [x(0..15) | delta(16) | h0(17..66) | zero(67..71)]      K0P=72
//  X1 (L1 input):  [h1(0..49) | zero(50,51) | h0(52..101) | zero(102,103)] K1P=104
//  FC:             [h1(0..49) | cols 50..63 zero-weighted]                 KFP=64
#define K0P 72
#define K1P 104
#define KFP 64

typedef _Float16 half_t;
typedef __attribute__((ext_vector_type(8))) _Float16 half8;
typedef __attribute__((ext_vector_type(4))) float    floatx4;

#define MFMA16(a, b, c) __builtin_amdgcn_mfma_f32_16x16x32_f16((a), (b), (c), 0, 0, 0)

__device__ __forceinline__ float sig_u(float x) {
    float e = __expf(-x);
    return __builtin_amdgcn_rcpf(1.0f + e);
}
__device__ __forceinline__ float tanh_u(float x) {
    float e = __expf(-2.0f * x);
    return fmaf(2.0f, __builtin_amdgcn_rcpf(1.0f + e), -1.0f);
}
// fp32 -> fp16 hi + fp16 lo (v ~= hi + lo to ~2^-22 rel; values here are < 16)
__device__ __forceinline__ void hsplit(float v, half_t* hp, half_t* lp) {
    half_t h = (half_t)v;
    *hp = h;
    *lp = (half_t)(v - (float)h);
}

__global__ __launch_bounds__(NTHREADS, 2)   // min 2 waves/EU -> VGPR cap 256, 2 blocks/CU
void lstm2_mfma_regw_kernel(const float* __restrict__ feat,
                            const float* __restrict__ w_ih0,
                            const float* __restrict__ w_hh0,
                            const float* __restrict__ b_0,
                            const float* __restrict__ w_ih1,
                            const float* __restrict__ w_hh1,
                            const float* __restrict__ b_1,
                            const float* __restrict__ w_fc1,
                            const float* __restrict__ b_fc1,
                            const float* __restrict__ w_fc2,
                            const float* __restrict__ b_fc2,
                            float* __restrict__ out)
{
    // 53 KB static LDS: W staging scratch (transient) + persistent X planes
    __shared__ __align__(16) half_t smW[200 * K1P];       // 41.6 KB scratch
    __shared__ __align__(16) half_t X0h[BT * K0P], X0l[BT * K0P];
    __shared__ __align__(16) half_t X1h[BT * K1P], X1l[BT * K1P];

    const int tid  = threadIdx.x;
    const int lane = tid & 63;
    const int wv   = tid >> 6;        // wave 0..3
    const int quad = lane >> 4;       // 0..3
    const int col  = lane & 15;       // sample / B-row
    const int b0   = blockIdx.x * BT;

    // wave -> M-tile assignment over 13 tiles: {0-2},{3-5},{6-9},{10-12}
    const int tstart = wv * 3 + (wv == 3 ? 1 : 0);
    const int tcnt   = 3 + (wv == 2 ? 1 : 0);

    const half8 hz = {0, 0, 0, 0, 0, 0, 0, 0};

    // ================= startup: stage -> register fragments =================
    // Unit-interleaved rows: row 4j+q = gate q (i,f,g,o) of unit j; orig = q*50+j.

    // ---- W0 ----
    for (int i = tid; i < 200 * K0P; i += NTHREADS) {
        int row = i / K0P, k = i - row * K0P;
        int j = row >> 2, q = row & 3, orig = q * HID + j;
        float v = 0.0f;
        if (k < IN0)            v = w_ih0[orig * IN0 + k];
        else if (k < IN0 + HID) v = w_hh0[orig * HID + (k - IN0)];
        smW[i] = (half_t)v;
    }
    __syncthreads();
    half8 a0f[3][4];
    #pragma unroll
    for (int kt = 0; kt < 3; ++kt) {
        int k0 = 32 * kt + quad * 8;
        #pragma unroll
        for (int ti = 0; ti < 4; ++ti) {
            a0f[kt][ti] = hz;
            int row = 16 * (tstart + ti) + col;
            if (ti < tcnt && row < 200 && k0 < K0P)
                a0f[kt][ti] = *(const half8*)(smW + row * K0P + k0);
        }
    }
    __syncthreads();   // frag reads done before scratch reuse

    // ---- W1 ----
    for (int i = tid; i < 200 * K1P; i += NTHREADS) {
        int row = i / K1P, k = i - row * K1P;
        int j = row >> 2, q = row & 3, orig = q * HID + j;
        float v = 0.0f;
        if (k < HID)                      v = w_hh1[orig * HID + k];          // x h1
        else if (k >= 52 && k < 52 + HID) v = w_ih1[orig * HID + (k - 52)];   // x h0
        smW[i] = (half_t)v;
    }
    __syncthreads();
    half8 a1f[4][4];
    #pragma unroll
    for (int kt = 0; kt < 4; ++kt) {
        int k0 = 32 * kt + quad * 8;
        #pragma unroll
        for (int ti = 0; ti < 4; ++ti) {
            a1f[kt][ti] = hz;
            int row = 16 * (tstart + ti) + col;
            if (ti < tcnt && row < 200 && k0 < K1P)
                a1f[kt][ti] = *(const half8*)(smW + row * K1P + k0);
        }
    }
    __syncthreads();

    // ---- Wf (32 x 64, rows >= 25 and k >= 50 zero) + X-plane zero-init ----
    for (int i = tid; i < 32 * KFP; i += NTHREADS) {
        int row = i >> 6, k = i & 63;
        smW[i] = (half_t)((row < 25 && k < HID) ? w_fc1[row * HID + k] : 0.0f);
    }
    for (int i = tid; i < BT * K0P; i += NTHREADS) { X0h[i] = (half_t)0.0f; X0l[i] = (half_t)0.0f; }
    for (int i = tid; i < BT * K1P; i += NTHREADS) { X1h[i] = (half_t)0.0f; X1l[i] = (half_t)0.0f; }
    __syncthreads();   // zero-init AND Wf staged before reads/feature writes (round-3 lesson)

    half8 wff[2][2];
    wff[0][0] = hz; wff[0][1] = hz; wff[1][0] = hz; wff[1][1] = hz;
    if (wv == 0) {
        #pragma unroll
        for (int kt = 0; kt < 2; ++kt) {
            int k0 = 32 * kt + quad * 8;        // <= 56 < 64
            #pragma unroll
            for (int tf = 0; tf < 2; ++tf) {
                int row = 16 * tf + col;        // < 32
                wff[kt][tf] = *(const half8*)(smW + row * KFP + k0);
            }
        }
    }

    // ---- t=0 features (256 threads cover 16 samples x 16 features) ----
    const int xs = tid >> 4, xk = tid & 15;
    const size_t fbase = (size_t)(b0 + xs) * (TSTEPS * SDIM) + xk;
    hsplit(feat[fbase], &X0h[xs * K0P + xk], &X0l[xs * K0P + xk]);

    // ---- per-lane biases (acc reg rho = gate rho of unit u = 4*mt + quad) ----
    floatx4 bias0[4], bias1[4];
    #pragma unroll
    for (int ti = 0; ti < 4; ++ti) {
        floatx4 z = {0.f, 0.f, 0.f, 0.f};
        bias0[ti] = z; bias1[ti] = z;
        int u = 4 * (tstart + ti) + quad;
        if (ti < tcnt && u < HID) {
            bias0[ti][0] = b_0[u];           bias0[ti][1] = b_0[HID + u];
            bias0[ti][2] = b_0[2 * HID + u]; bias0[ti][3] = b_0[3 * HID + u];
            bias1[ti][0] = b_1[u];           bias1[ti][1] = b_1[HID + u];
            bias1[ti][2] = b_1[2 * HID + u]; bias1[ti][3] = b_1[3 * HID + u];
        }
    }
    // FC constants (wave 0): C row = 16*tf + quad*4 + r5
    floatx4 w2r[2], bfr[2];
    { floatx4 z = {0.f, 0.f, 0.f, 0.f}; w2r[0] = z; w2r[1] = z; bfr[0] = z; bfr[1] = z; }
    float bf2 = 0.0f;
    if (wv == 0) {
        bf2 = b_fc2[0];
        #pragma unroll
        for (int tf = 0; tf < 2; ++tf)
            #pragma unroll
            for (int r5 = 0; r5 < 4; ++r5) {
                int r = 16 * tf + quad * 4 + r5;
                if (r < 25) { w2r[tf][r5] = w_fc2[r]; bfr[tf][r5] = b_fc1[r]; }
            }
    }

    float c0s[4] = {0.f, 0.f, 0.f, 0.f};
    float c1s[4] = {0.f, 0.f, 0.f, 0.f};
    __syncthreads();

    // ================= time loop =================
    for (int t = 0; t < TSTEPS; ++t) {
        float fnext = (t + 1 < TSTEPS) ? feat[fbase + (size_t)(t + 1) * SDIM] : 0.0f;

        // ===== P1: layer-0 gates, 2-product fp16 MFMA (A in registers) =====
        floatx4 acc[4];
        #pragma unroll
        for (int ti = 0; ti < 4; ++ti) acc[ti] = bias0[ti];
        #pragma unroll
        for (int kt = 0; kt < 3; ++kt) {
            int k0 = 32 * kt + quad * 8;
            half8 bh = hz, bl = hz;
            if (k0 < K0P) {
                bh = *(const half8*)(X0h + col * K0P + k0);
                bl = *(const half8*)(X0l + col * K0P + k0);
            }
            #pragma unroll
            for (int ti = 0; ti < 4; ++ti) {
                if (ti < tcnt) {
                    acc[ti] = MFMA16(a0f[kt][ti], bh, acc[ti]);
                    acc[ti] = MFMA16(a0f[kt][ti], bl, acc[ti]);
                }
            }
        }
        __syncthreads();   // B1: X0 reads done before h0 writes

        // ===== P2: layer-0 cell update (registers) =====
        #pragma unroll
        for (int ti = 0; ti < 4; ++ti) {
            if (ti < tcnt) {
                int u = 4 * (tstart + ti) + quad;
                float i_ = sig_u(acc[ti][0]);
                float f_ = sig_u(acc[ti][1]);
                float g_ = tanh_u(acc[ti][2]);
                float o_ = sig_u(acc[ti][3]);
                float c  = f_ * c0s[ti] + i_ * g_;
                c0s[ti]  = c;
                float h  = o_ * tanh_u(c);
                half_t hh, hl;
                hsplit(h, &hh, &hl);
                X1h[col * K1P + 52 + u] = hh;  X1l[col * K1P + 52 + u] = hl;   // L1 input
                X0h[col * K0P + IN0 + u] = hh; X0l[col * K0P + IN0 + u] = hl;  // next-step L0
            }
        }
        __syncthreads();   // B2: h0 staged before L1 reads

        // ===== P3: layer-1 gates =====
        floatx4 acc1[4];
        #pragma unroll
        for (int ti = 0; ti < 4; ++ti) acc1[ti] = bias1[ti];
        #pragma unroll
        for (int kt = 0; kt < 4; ++kt) {
            int k0 = 32 * kt + quad * 8;
            half8 bh = hz, bl = hz;
            if (k0 < K1P) {
                bh = *(const half8*)(X1h + col * K1P + k0);
                bl = *(const half8*)(X1l + col * K1P + k0);
            }
            #pragma unroll
            for (int ti = 0; ti < 4; ++ti) {
                if (ti < tcnt) {
                    acc1[ti] = MFMA16(a1f[kt][ti], bh, acc1[ti]);
                    acc1[ti] = MFMA16(a1f[kt][ti], bl, acc1[ti]);
                }
            }
        }
        __syncthreads();   // B3: X1 reads done before h1 writes

        // ===== P4: layer-1 cell update =====
        #pragma unroll
        for (int ti = 0; ti < 4; ++ti) {
            if (ti < tcnt) {
                int u = 4 * (tstart + ti) + quad;
                float i_ = sig_u(acc1[ti][0]);
                float f_ = sig_u(acc1[ti][1]);
                float g_ = tanh_u(acc1[ti][2]);
                float o_ = sig_u(acc1[ti][3]);
                float c  = f_ * c1s[ti] + i_ * g_;
                c1s[ti]  = c;
                float h  = o_ * tanh_u(c);
                half_t hh, hl;
                hsplit(h, &hh, &hl);
                X1h[col * K1P + u] = hh;  X1l[col * K1P + u] = hl;   // FC input + next L1
            }
        }
        __syncthreads();   // B4: h1 staged before FC reads

        // ===== P5: FC head (wave 0) + feature staging (all) =====
        if (wv == 0) {
            floatx4 accf[2];
            accf[0] = bfr[0]; accf[1] = bfr[1];
            #pragma unroll
            for (int kt = 0; kt < 2; ++kt) {
                int k0 = 32 * kt + quad * 8;   // <= 56: in-row; cols 50..63 zero-weighted
                half8 bh = *(const half8*)(X1h + col * K1P + k0);
                half8 bl = *(const half8*)(X1l + col * K1P + k0);
                #pragma unroll
                for (int tf = 0; tf < 2; ++tf) {
                    accf[tf] = MFMA16(wff[kt][tf], bh, accf[tf]);
                    accf[tf] = MFMA16(wff[kt][tf], bl, accf[tf]);
                }
            }
            float p = 0.0f;
            #pragma unroll
            for (int tf = 0; tf < 2; ++tf)
                #pragma unroll
                for (int r5 = 0; r5 < 4; ++r5)
                    p += w2r[tf][r5] * fmaxf(accf[tf][r5], 0.0f);
            p += __shfl_xor(p, 16);
            p += __shfl_xor(p, 32);
            float d = p + bf2;
            if (lane < 16) {
                out[(size_t)(b0 + lane) * TSTEPS + t] = d;
                hsplit(d, &X0h[lane * K0P + 16], &X0l[lane * K0P + 16]);  // prev_delta
            }
        }
        if (t + 1 < TSTEPS)
            hsplit(fnext, &X0h[xs * K0P + xk], &X0l[xs * K0P + xk]);
        __syncthreads();   // B5: X0 fully staged for next step
    }
}

extern "C" void kernel_launch(void* const* d_in, const int* in_sizes, int n_in,
                              void* d_out, int out_size, void* d_ws, size_t ws_size,
                              hipStream_t stream) {
    const float* feat  = (const float*)d_in[0];
    const float* w_ih0 = (const float*)d_in[1];
    const float* w_hh0 = (const float*)d_in[2];
    const float* b_0   = (const float*)d_in[3];
    const float* w_ih1 = (const float*)d_in[4];
    const float* w_hh1 = (const float*)d_in[5];
    const float* b_1   = (const float*)d_in[6];
    const float* w_fc1 = (const float*)d_in[7];
    const float* b_fc1 = (const float*)d_in[8];
    const float* w_fc2 = (const float*)d_in[9];
    const float* b_fc2 = (const float*)d_in[10];
    float* out = (float*)d_out;

    dim3 grid(BATCH / BT);   // 512 blocks; 53 KB LDS + <=256 VGPR -> 2 blocks/CU, all resident
    dim3 block(NTHREADS);
    hipLaunchKernelGGL(lstm2_mfma_regw_kernel, grid, block, 0, stream,
                       feat, w_ih0, w_hh0, b_0, w_ih1, w_hh1, b_1,
                       w_fc1, b_fc1, w_fc2, b_fc2, out);
}